// Round 7
// baseline (128.096 us; speedup 1.0000x reference)
//
#include <hip/hip_runtime.h>

#define Bq 4
#define Cc 2048
#define Ss 1024
#define Hh 16
#define Dd 128

// 1/sqrt(128) * log2(e): softmax runs in exp2 domain, folded into Q at prep
#define QSCALE 0.127517429f

typedef __bf16 bf16x8 __attribute__((ext_vector_type(8)));
typedef float  f32x4  __attribute__((ext_vector_type(4)));

__device__ __forceinline__ ushort f2bf(float f) {
    uint u = __float_as_uint(f);
    u += 0x7FFFu + ((u >> 16) & 1u);   // RNE
    return (ushort)(u >> 16);
}
__device__ __forceinline__ uint pack2bf(float a, float b) {
    return (uint)f2bf(a) | ((uint)f2bf(b) << 16);
}
__device__ __forceinline__ void gld16(const void* g, void* l) {
    __builtin_amdgcn_global_load_lds(
        (const __attribute__((address_space(1))) unsigned int*)g,
        (__attribute__((address_space(3))) unsigned int*)l, 16, 0, 0);
}

// ---------------------------------------------------------------------------
// mask -> additive bias (0 / -1e30), runtime dtype detection (bool/int/float)
// ---------------------------------------------------------------------------
__global__ __launch_bounds__(256) void mask_bias_k(const unsigned* __restrict__ mask,
                                                   float* __restrict__ bias) {
    __shared__ int f01, ff;
    const int t = threadIdx.x;
    if (t == 0) { f01 = 0; ff = 0; }
    __syncthreads();
    int a = 0, b = 0;
    for (int i = t; i < 1024; i += 256) {
        unsigned v = mask[i];
        if (v != 0u && v != 1u) a = 1;
        if (v != 0u && v != 0x3F800000u) b = 1;
    }
    if (a) atomicOr(&f01, 1);
    if (b) atomicOr(&ff, 1);
    __syncthreads();
    const int mode = f01 ? (ff ? 1 : 2) : 0;
    const int* mi = (const int*)mask;
    const unsigned char* mb = (const unsigned char*)mask;
    const float* mf = (const float*)mask;
    for (int i = t; i < Bq * Ss; i += 256) {
        bool on;
        if (mode == 0)      on = (mi[i] != 0);
        else if (mode == 1) on = (mb[i] != 0);
        else                on = (mf[i] != 0.0f);
        bias[i] = on ? 0.0f : -1e30f;
    }
}

// ---------------------------------------------------------------------------
// W fp32[2048][2048] -> bf16 with intra-128B XOR swizzle (by row&7)
// ---------------------------------------------------------------------------
__global__ __launch_bounds__(256) void wcvt_swz(const float* __restrict__ w,
                                                ushort* __restrict__ wb) {
    const size_t e = ((size_t)blockIdx.x * 256 + threadIdx.x) * 8;
    const int row = (int)(e >> 11), col = (int)(e & 2047);
    const int colS = (col & ~63) | ((col & 63) ^ ((row & 7) << 3));
    float4 v0 = *(const float4*)&w[e];
    float4 v1 = *(const float4*)&w[e + 4];
    uint4 o;
    o.x = pack2bf(v0.x, v0.y); o.y = pack2bf(v0.z, v0.w);
    o.z = pack2bf(v1.x, v1.y); o.w = pack2bf(v1.z, v1.w);
    *(uint4*)&wb[(size_t)row * 2048 + colS] = o;
}

// ---------------------------------------------------------------------------
// V fp32[8192][1024] -> bf16, k-PERMUTED within each 64-col block:
//   k' = 32*(k>>5) + 8*((k>>2)&3) + 4*((k>>4)&1) + (k&3)
// (matches in-register P layout of swapped-QK MFMA), + intra-128B XOR
// swizzle (by row&7). Thread handles one 8-k'-aligned output uint4.
// ---------------------------------------------------------------------------
__global__ __launch_bounds__(256) void vcvt_perm(const float* __restrict__ v,
                                                 ushort* __restrict__ vb) {
    const int tid = blockIdx.x * 256 + threadIdx.x;   // 0 .. 1M-1
    const int row = tid >> 7;                          // 0..8191
    const int cp = tid & 127;
    const int blk = (cp >> 3) * 64;                    // 64-col block
    const int j0 = cp & 7;                             // 8-k' group
    const int b5 = j0 >> 2, h = j0 & 3;
    const float* src = v + (size_t)row * 1024 + blk + 32 * b5 + 4 * h;
    float4 A = *(const float4*)src;            // ns = 2*b5,   r = 0..3
    float4 B = *(const float4*)(src + 16);     // ns = 2*b5+1, r = 0..3
    uint4 o;
    o.x = pack2bf(A.x, A.y); o.y = pack2bf(A.z, A.w);
    o.z = pack2bf(B.x, B.y); o.w = pack2bf(B.z, B.w);
    *(uint4*)&vb[(size_t)row * 1024 + blk + ((j0 * 8) ^ ((row & 7) << 3))] = o;
}

// ---------------------------------------------------------------------------
// Q/K transpose+convert: [d 128][S] fp32 -> [S][d 128] bf16 per (b,h).
// Q (z=0): scaled by QSCALE, no swizzle. K (z=1): XOR swizzle by k&7.
// ---------------------------------------------------------------------------
__global__ __launch_bounds__(256) void qk_prep(const float* __restrict__ queries,
                                               const float* __restrict__ keys,
                                               ushort* __restrict__ Qt,
                                               ushort* __restrict__ Kt) {
    __shared__ float T[128][65];
    const int t = threadIdx.x;
    const int s0 = blockIdx.x * 64;
    const int bh = blockIdx.y;
    const int isK = blockIdx.z;
    const float* src = (isK ? keys : queries) + (size_t)bh * 128 * 1024;
    const float sc = isK ? 1.0f : QSCALE;

#pragma unroll
    for (int p = 0; p < 8; ++p) {
        const int d = p * 16 + (t >> 4);
        float4 v = *(const float4*)&src[(size_t)d * 1024 + s0 + (t & 15) * 4];
        T[d][(t & 15) * 4 + 0] = v.x * sc;
        T[d][(t & 15) * 4 + 1] = v.y * sc;
        T[d][(t & 15) * 4 + 2] = v.z * sc;
        T[d][(t & 15) * 4 + 3] = v.w * sc;
    }
    __syncthreads();

    ushort* outp = isK ? Kt : Qt;
#pragma unroll
    for (int p = 0; p < 4; ++p) {
        const int k = p * 16 + (t >> 4);
        const int x = t & 15;
        uint4 o;
        o.x = pack2bf(T[x * 8 + 0][k], T[x * 8 + 1][k]);
        o.y = pack2bf(T[x * 8 + 2][k], T[x * 8 + 3][k]);
        o.z = pack2bf(T[x * 8 + 4][k], T[x * 8 + 5][k]);
        o.w = pack2bf(T[x * 8 + 6][k], T[x * 8 + 7][k]);
        const size_t rowbyte = ((size_t)bh * 1024 + s0 + k) * 256;
        const int boff = isK ? ((x * 16) ^ ((k & 7) << 4)) : (x * 16);
        *(uint4*)((char*)outp + rowbyte + boff) = o;
    }
}

// ---------------------------------------------------------------------------
// MFMA flash attention v6. Same structure as v5 (256 blocks x 512 thr, q-tile
// 256, KVBLK 64 triple-buffered, counted vmcnt(4)), with the mask bias folded
// into the QK MFMA C-initializer (row r of D = k = ns*16+g*4+r).
// ---------------------------------------------------------------------------
__global__ __launch_bounds__(512, 2) void attn6(const ushort* __restrict__ Qt,
                                                const ushort* __restrict__ Kt,
                                                const ushort* __restrict__ Vbf,
                                                const float* __restrict__ bias,
                                                ushort* __restrict__ hidT) {
    __shared__ __align__(16) char SMEM[102400];
    // K: 3 x [64][128] (16 KB each) at 0; V: 3 x [128][64] at 49152; bias 98304
    float* biasS = (float*)(SMEM + 98304);

    const int t = threadIdx.x, l = t & 63, w = t >> 6;   // w = 0..7
    const int kk = l & 15, g = l >> 4;

    const int bid = blockIdx.x;
    const int vid = (bid & 7) * 32 + (bid >> 3);   // XCD-affine (256 blocks)
    const int bh = vid >> 2, qt = vid & 3;
    const int b = bh >> 4;
    const int q0 = qt * 256;
    const size_t bhbase = (size_t)bh * 1024;

    for (int i = t; i < Ss; i += 512) biasS[i] = bias[b * Ss + i];

    // Q fragments (B-operand): lane kk holds q-row, d-slice g*8 + 32*dc
    bf16x8 qf[2][4];
#pragma unroll
    for (int qs = 0; qs < 2; ++qs) {
        const ushort* qrow = Qt + (bhbase + q0 + w * 32 + qs * 16 + kk) * 128;
#pragma unroll
        for (int dc = 0; dc < 4; ++dc)
            qf[qs][dc] = *(const bf16x8*)(qrow + dc * 32 + g * 8);
    }

    float lrun[2] = {0.0f, 0.0f};
    f32x4 hacc[2][8];
#pragma unroll
    for (int qs = 0; qs < 2; ++qs)
#pragma unroll
        for (int i = 0; i < 8; ++i) hacc[qs][i] = (f32x4){0.f, 0.f, 0.f, 0.f};

    // stage chunk cki into buffer bufi (4 gld16 per thread: 2 K + 2 V)
#define ATTN_STAGE(bufi, cki)                                                   \
    {                                                                           \
        const int k0n = (cki) * 64;                                             \
        ushort* Kd = (ushort*)SMEM + (bufi) * 8192;                             \
        ushort* Vd = (ushort*)(SMEM + 49152) + (bufi) * 8192;                   \
        _Pragma("unroll")                                                       \
        for (int ii = 0; ii < 4; ++ii) {                                        \
            const int inst = ii * 8 + w;                                        \
            if (inst < 16) {                                                    \
                gld16(Kt + (bhbase + k0n + inst * 4 + (l >> 4)) * 128 +         \
                          (l & 15) * 8,                                         \
                      Kd + inst * 512);                                         \
            } else {                                                            \
                const int i2 = inst - 16;                                       \
                gld16(Vbf + ((size_t)bh * 128 + i2 * 8 + (l >> 3)) * 1024 +     \
                          k0n + (l & 7) * 8,                                    \
                      Vd + i2 * 512);                                           \
            }                                                                   \
        }                                                                       \
    }

    // one chunk of compute from buffer bi; bias enters as MFMA C-init
#define ATTN_COMPUTE(bi, ck)                                                     \
    {                                                                            \
        const int k0 = (ck) * 64;                                                \
        const ushort* KTb = (const ushort*)SMEM + (bi) * 8192;                   \
        const ushort* Vsb = (const ushort*)(SMEM + 49152) + (bi) * 8192;         \
        f32x4 sc[2][4];                                                          \
        __builtin_amdgcn_s_setprio(1);                                           \
        _Pragma("unroll")                                                        \
        for (int ns = 0; ns < 4; ++ns) {                                         \
            const f32x4 ci = *(const f32x4*)&biasS[k0 + ns * 16 + g * 4];        \
            bf16x8 kf[4];                                                        \
            const ushort* kr = KTb + (ns * 16 + kk) * 128;                       \
            _Pragma("unroll")                                                    \
            for (int dc = 0; dc < 4; ++dc)                                       \
                kf[dc] = *(const bf16x8*)(kr +                                   \
                             ((dc * 32 + g * 8) ^ ((kk & 7) << 3)));             \
            _Pragma("unroll")                                                    \
            for (int qs = 0; qs < 2; ++qs) {                                     \
                f32x4 a = ci;                                                    \
                _Pragma("unroll")                                                \
                for (int dc = 0; dc < 4; ++dc)                                   \
                    a = __builtin_amdgcn_mfma_f32_16x16x32_bf16(                 \
                        kf[dc], qf[qs][dc], a, 0, 0, 0);                         \
                sc[qs][ns] = a;                                                  \
            }                                                                    \
        }                                                                        \
        __builtin_amdgcn_s_setprio(0);                                           \
        bf16x8 pb[2][2];                                                         \
        _Pragma("unroll")                                                        \
        for (int qs = 0; qs < 2; ++qs) {                                         \
            float pv[4][4];                                                      \
            float s = 0.0f;                                                      \
            _Pragma("unroll")                                                    \
            for (int ns = 0; ns < 4; ++ns) {                                     \
                _Pragma("unroll")                                                \
                for (int r = 0; r < 4; ++r) {                                    \
                    float p = exp2f(sc[qs][ns][r]);                              \
                    pv[ns][r] = p;                                               \
                    s += p;                                                      \
                }                                                                \
            }                                                                    \
            lrun[qs] += s;                                                       \
            _Pragma("unroll")                                                    \
            for (int kh = 0; kh < 2; ++kh) {                                     \
                bf16x8 vpk;                                                      \
                _Pragma("unroll")                                                \
                for (int j = 0; j < 8; ++j)                                      \
                    vpk[j] = (__bf16)pv[2 * kh + (j >> 2)][j & 3];               \
                pb[qs][kh] = vpk;                                                \
            }                                                                    \
        }                                                                        \
        __builtin_amdgcn_s_setprio(1);                                           \
        _Pragma("unroll")                                                        \
        for (int kh = 0; kh < 2; ++kh) {                                         \
            _Pragma("unroll")                                                    \
            for (int ds = 0; ds < 8; ++ds) {                                     \
                bf16x8 vf = *(const bf16x8*)(Vsb + (ds * 16 + kk) * 64 +         \
                                 ((kh * 32 + g * 8) ^ ((kk & 7) << 3)));         \
                hacc[0][ds] = __builtin_amdgcn_mfma_f32_16x16x32_bf16(           \
                    vf, pb[0][kh], hacc[0][ds], 0, 0, 0);                        \
                hacc[1][ds] = __builtin_amdgcn_mfma_f32_16x16x32_bf16(           \
                    vf, pb[1][kh], hacc[1][ds], 0, 0, 0);                        \
            }                                                                    \
        }                                                                        \
        __builtin_amdgcn_s_setprio(0);                                           \
    }

    // prologue: 2 tiles in flight; wait for tile 0 only (counted)
    ATTN_STAGE(0, 0);
    ATTN_STAGE(1, 1);
    asm volatile("s_waitcnt vmcnt(4)" ::: "memory");
    __builtin_amdgcn_s_barrier();

    int cb = 0, sb = 2;
    for (int ck = 0; ck < 14; ++ck) {
        ATTN_STAGE(sb, ck + 2);
        ATTN_COMPUTE(cb, ck);
        asm volatile("s_waitcnt vmcnt(4)" ::: "memory");  // next tile landed
        __builtin_amdgcn_s_barrier();
        cb = (cb == 2) ? 0 : cb + 1;
        sb = (sb == 2) ? 0 : sb + 1;
    }
    // tail: no more stages
    ATTN_COMPUTE(cb, 14);
    asm volatile("s_waitcnt vmcnt(0)" ::: "memory");
    __builtin_amdgcn_s_barrier();
    cb = (cb == 2) ? 0 : cb + 1;
    ATTN_COMPUTE(cb, 15);
#undef ATTN_STAGE
#undef ATTN_COMPUTE

    // l: sum partial sums across the 4 g-groups
    float linv[2];
#pragma unroll
    for (int qs = 0; qs < 2; ++qs) {
        float s = lrun[qs];
        s += __shfl_xor(s, 16);
        s += __shfl_xor(s, 32);
        linv[qs] = 1.0f / s;
    }

    __syncthreads();   // done with K/V buffers; reuse as [256 q][128 d] stage
    {
        ushort* hs = (ushort*)SMEM;
#pragma unroll
        for (int qs = 0; qs < 2; ++qs) {
            const int row = w * 32 + qs * 16 + kk;
#pragma unroll
            for (int ds = 0; ds < 8; ++ds) {
                uint2 pk;
                pk.x = pack2bf(hacc[qs][ds][0] * linv[qs], hacc[qs][ds][1] * linv[qs]);
                pk.y = pack2bf(hacc[qs][ds][2] * linv[qs], hacc[qs][ds][3] * linv[qs]);
                const int off = row * 256 + ((ds * 32 + g * 8) ^ ((row & 7) << 4));
                *(uint2*)((char*)hs + off) = pk;
            }
        }
    }
    __syncthreads();

    const int hh = bh & 15;
    const char* hsb = (const char*)SMEM;
#pragma unroll
    for (int it = 0; it < 8; ++it) {
        const int idx = it * 512 + t;                  // 0..4095
        const int q = idx >> 4, x = idx & 15;
        uint4 vv = *(const uint4*)(hsb + q * 256 + x * 16);
        *(uint4*)((char*)hidT + ((size_t)(b * Ss + q0 + q)) * 4096 + hh * 256 + x * 16) = vv;
    }
}

// ---------------------------------------------------------------------------
// proj4: out[2048][4096] = W @ hidT^T. BM=128, BN=256, BK=64, 512 thr
// (8 waves 2Mx4N, per-wave 64x64). 3-buffer LDS (144 KB), 4-phase/K-tile
// schedule: {ds_read ∥ gld16-issue -> barrier -> lgkmcnt(0) -> setprio ->
// 8 MFMA -> barrier}; vmcnt(6) once per K-tile (T3+T4). 256 blocks (1/CU).
// ---------------------------------------------------------------------------
__global__ __launch_bounds__(512, 2) void proj4(const ushort* __restrict__ Wbf,
                                                const ushort* __restrict__ hidT,
                                                float* __restrict__ out) {
    __shared__ __align__(16) char SMEM[147456];
    // A: 3 x [128][64] (16 KB) at 0; B: 3 x [256][64] (32 KB) at 49152
    const int t = threadIdx.x, l = t & 63, w = t >> 6;
    const int kk = l & 15, g = l >> 4;
    const int wr = w >> 2, wc = w & 3;

    const int bid = blockIdx.x;
    const int vid = (bid & 7) * 32 + (bid >> 3);   // 256 blocks, XCD-bijective
    const int o0 = (vid & 15) * 128;               // 16 M-tiles
    const int n0 = (vid >> 4) * 256;               // 16 N-tiles

    f32x4 acc[4][4];
#pragma unroll
    for (int i = 0; i < 4; ++i)
#pragma unroll
        for (int j = 0; j < 4; ++j) acc[i][j] = (f32x4){0.f, 0.f, 0.f, 0.f};

    const int swz = ((kk & 7) << 3);

#define P4_STAGE_A(st, ks)                                                      \
    {                                                                           \
        ushort* Ad = (ushort*)SMEM + (st) * 8192;                               \
        _Pragma("unroll")                                                       \
        for (int ii = 0; ii < 2; ++ii) {                                        \
            const int i = ii * 8 + w;                                           \
            gld16(Wbf + (size_t)(o0 + i * 8 + (l >> 3)) * 2048 + (ks) * 64 +    \
                      (l & 7) * 8,                                              \
                  Ad + i * 512);                                                \
        }                                                                       \
    }
#define P4_STAGE_B(st, ks, jj0)                                                 \
    {                                                                           \
        ushort* Bd = (ushort*)(SMEM + 49152) + (st) * 16384;                    \
        _Pragma("unroll")                                                       \
        for (int jj = (jj0); jj < (jj0) + 2; ++jj) {                            \
            const int j = jj * 8 + w;                                           \
            gld16(hidT + (size_t)(n0 + j * 8 + (l >> 3)) * 2048 + (ks) * 64 +   \
                      (l & 7) * 8,                                              \
                  Bd + j * 512);                                                \
        }                                                                       \
    }
#define P4_MFMA(nsv)                                                            \
    __builtin_amdgcn_s_setprio(1);                                              \
    _Pragma("unroll")                                                           \
    for (int dc = 0; dc < 2; ++dc)                                              \
        _Pragma("unroll")                                                       \
        for (int ms = 0; ms < 4; ++ms)                                          \
            acc[ms][nsv] = __builtin_amdgcn_mfma_f32_16x16x32_bf16(             \
                af[dc][ms], bfr[dc], acc[ms][nsv], 0, 0, 0);                    \
    __builtin_amdgcn_s_setprio(0);
#define P4_BF(nsv)                                                              \
    _Pragma("unroll")                                                           \
    for (int dc = 0; dc < 2; ++dc)                                              \
        bfr[dc] = *(const bf16x8*)&Bb[(wc * 64 + (nsv) * 16 + kk) * 64 +        \
                                      ((dc * 32 + g * 8) ^ swz)];
#define P4_BAR()  __builtin_amdgcn_s_barrier()
#define P4_LGKM() asm volatile("s_waitcnt lgkmcnt(0)" ::: "memory")

    // prologue: stage tiles 0 and 1; wait for tile 0 only
    P4_STAGE_A(0, 0); P4_STAGE_B(0, 0, 0); P4_STAGE_B(0, 0, 2);
    P4_STAGE_A(1, 1); P4_STAGE_B(1, 1, 0); P4_STAGE_B(1, 1, 2);
    asm volatile("s_waitcnt vmcnt(6)" ::: "memory");
    P4_BAR();

    int ct = 0, st = 2;
    for (int tt = 0; tt < 32; ++tt) {
        const ushort* Ab = (const ushort*)SMEM + ct * 8192;
        const ushort* Bb = (const ushort*)(SMEM + 49152) + ct * 16384;
        const int ksS = tt + 2;
        bf16x8 af[2][4], bfr[2];

        // ---- phase 0: af (8 reads) + bf[ns=0]; issue A-stage ----
#pragma unroll
        for (int dc = 0; dc < 2; ++dc)
#pragma unroll
            for (int ms = 0; ms < 4; ++ms)
                af[dc][ms] = *(const bf16x8*)&Ab[(wr * 64 + ms * 16 + kk) * 64 +
                                                 ((dc * 32 + g * 8) ^ swz)];
        P4_BF(0);
        if (tt < 30) P4_STAGE_A(st, ksS);
        P4_BAR(); P4_LGKM();
        P4_MFMA(0);
        P4_BAR();

        // ---- phase 1: bf[ns=1]; issue B-stage part 0 ----
        P4_BF(1);
        if (tt < 30) P4_STAGE_B(st, ksS, 0);
        P4_BAR(); P4_LGKM();
        P4_MFMA(1);
        P4_BAR();

        // ---- phase 2: bf[ns=2]; issue B-stage part 1 ----
        P4_BF(2);
        if (tt < 30) P4_STAGE_B(st, ksS, 2);
        P4_BAR(); P4_LGKM();
        P4_MFMA(2);
        P4_BAR();

        // ---- phase 3: bf[ns=3]; counted wait for NEXT tile ----
        P4_BF(3);
        if (tt < 30)       { asm volatile("s_waitcnt vmcnt(6)" ::: "memory"); }
        else if (tt == 30) { asm volatile("s_waitcnt vmcnt(0)" ::: "memory"); }
        P4_BAR(); P4_LGKM();
        P4_MFMA(3);
        P4_BAR();

        ct = (ct == 2) ? 0 : ct + 1;
        st = (st == 2) ? 0 : st + 1;
    }
#undef P4_STAGE_A
#undef P4_STAGE_B
#undef P4_MFMA
#undef P4_BF
#undef P4_BAR
#undef P4_LGKM

#pragma unroll
    for (int ms = 0; ms < 4; ++ms)
#pragma unroll
        for (int ns = 0; ns < 4; ++ns) {
            const int o = o0 + wr * 64 + ms * 16 + g * 4;
            const int n = n0 + wc * 64 + ns * 16 + kk;
            const int bb = n >> 10, qq = n & 1023;
            float* op = out + ((size_t)(bb * Cc + o)) * Ss + qq;
#pragma unroll
            for (int r = 0; r < 4; ++r) op[(size_t)r * Ss] = acc[ms][ns][r];
        }
}

extern "C" void kernel_launch(void* const* d_in, const int* in_sizes, int n_in,
                              void* d_out, int out_size, void* d_ws, size_t ws_size,
                              hipStream_t stream) {
    const float*    keys    = (const float*)d_in[0];
    const float*    values  = (const float*)d_in[1];
    const float*    queries = (const float*)d_in[2];
    const unsigned* mask    = (const unsigned*)d_in[3];
    const float*    w_out   = (const float*)d_in[4];
    float* out = (float*)d_out;

    char* ws = (char*)d_ws;
    float*  bias = (float*)ws;                              // 16 KB
    ushort* Wbf  = (ushort*)(ws + 16384);                   // 8 MB
    ushort* Qt   = (ushort*)(ws + 16384 + (8u << 20));      // 16 MB
    ushort* Kt   = (ushort*)(ws + 16384 + (24u << 20));     // 16 MB
    ushort* Vbf  = (ushort*)(ws + 16384 + (40u << 20));     // 16 MB
    ushort* hidT = (ushort*)(ws + 16384 + (56u << 20));     // 16 MB

    hipLaunchKernelGGL(mask_bias_k, dim3(1), dim3(256), 0, stream, mask, bias);
    hipLaunchKernelGGL(wcvt_swz, dim3(2048), dim3(256), 0, stream, w_out, Wbf);
    hipLaunchKernelGGL(vcvt_perm, dim3(4096), dim3(256), 0, stream, values, Vbf);
    hipLaunchKernelGGL(qk_prep, dim3(16, 64, 2), dim3(256), 0, stream,
                       queries, keys, Qt, Kt);
    hipLaunchKernelGGL(attn6, dim3(256), dim3(512), 0, stream,
                       Qt, Kt, Vbf, bias, hidT);
    hipLaunchKernelGGL(proj4, dim3(256), dim3(512), 0, stream,
                       Wbf, hidT, out);
}

// Round 8
// 114.804 us; speedup vs baseline: 1.1158x; 1.1158x over previous
//
#include <hip/hip_runtime.h>

#define Bq 4
#define Cc 2048
#define Ss 1024
#define Hh 16
#define Dd 128

// 1/sqrt(128) * log2(e): softmax runs in exp2 domain, folded into Q at load
#define QSCALE 0.127517429f

typedef __bf16 bf16x8 __attribute__((ext_vector_type(8)));
typedef float  f32x4  __attribute__((ext_vector_type(4)));

__device__ __forceinline__ ushort f2bf(float f) {
    uint u = __float_as_uint(f);
    u += 0x7FFFu + ((u >> 16) & 1u);   // RNE
    return (ushort)(u >> 16);
}
__device__ __forceinline__ uint pack2bf(float a, float b) {
    return (uint)f2bf(a) | ((uint)f2bf(b) << 16);
}
__device__ __forceinline__ void gld16(const void* g, void* l) {
    __builtin_amdgcn_global_load_lds(
        (const __attribute__((address_space(1))) unsigned int*)g,
        (__attribute__((address_space(3))) unsigned int*)l, 16, 0, 0);
}

// ---------------------------------------------------------------------------
// prep_all: one kernel, three block-ranges.
//   [0,2048)    W fp32[2048][2048] -> bf16, intra-128B XOR swizzle (row&7)
//   [2048,6144) V fp32[8192][1024] -> bf16, k-permuted within 64-col block
//               (k' matches swapped-QK P register layout) + XOR swizzle
//   [6144,7168) K transpose: [d 128][S] fp32 -> [S][128] bf16 per bh,
//               XOR swizzle by k&7
// ---------------------------------------------------------------------------
__global__ __launch_bounds__(256) void prep_all(const float* __restrict__ w,
                                                const float* __restrict__ v,
                                                const float* __restrict__ keys,
                                                ushort* __restrict__ wb,
                                                ushort* __restrict__ vb,
                                                ushort* __restrict__ Kt) {
    __shared__ __align__(16) float T[128][65];
    const int t = threadIdx.x;
    const int blk = blockIdx.x;

    if (blk < 2048) {
        // ---- W convert+swizzle ----
        const size_t e = ((size_t)blk * 256 + t) * 8;
        const int row = (int)(e >> 11), col = (int)(e & 2047);
        const int colS = (col & ~63) | ((col & 63) ^ ((row & 7) << 3));
        float4 v0 = *(const float4*)&w[e];
        float4 v1 = *(const float4*)&w[e + 4];
        uint4 o;
        o.x = pack2bf(v0.x, v0.y); o.y = pack2bf(v0.z, v0.w);
        o.z = pack2bf(v1.x, v1.y); o.w = pack2bf(v1.z, v1.w);
        *(uint4*)&wb[(size_t)row * 2048 + colS] = o;
    } else if (blk < 6144) {
        // ---- V convert + k-permute + swizzle ----
        const int tid = (blk - 2048) * 256 + t;    // 0 .. 1M-1
        const int row = tid >> 7;                   // 0..8191
        const int cp = tid & 127;
        const int blk64 = (cp >> 3) * 64;
        const int j0 = cp & 7;
        const int b5 = j0 >> 2, h = j0 & 3;
        const float* src = v + (size_t)row * 1024 + blk64 + 32 * b5 + 4 * h;
        float4 A = *(const float4*)src;
        float4 B = *(const float4*)(src + 16);
        uint4 o;
        o.x = pack2bf(A.x, A.y); o.y = pack2bf(A.z, A.w);
        o.z = pack2bf(B.x, B.y); o.w = pack2bf(B.z, B.w);
        *(uint4*)&vb[(size_t)row * 1024 + blk64 + ((j0 * 8) ^ ((row & 7) << 3))] = o;
    } else {
        // ---- K transpose+convert+swizzle ----
        const int b2 = blk - 6144;
        const int s0 = (b2 & 15) * 64;
        const int bh = b2 >> 4;
        const float* src = keys + (size_t)bh * 128 * 1024;
#pragma unroll
        for (int p = 0; p < 8; ++p) {
            const int d = p * 16 + (t >> 4);
            float4 v4 = *(const float4*)&src[(size_t)d * 1024 + s0 + (t & 15) * 4];
            T[d][(t & 15) * 4 + 0] = v4.x;
            T[d][(t & 15) * 4 + 1] = v4.y;
            T[d][(t & 15) * 4 + 2] = v4.z;
            T[d][(t & 15) * 4 + 3] = v4.w;
        }
        __syncthreads();
#pragma unroll
        for (int p = 0; p < 4; ++p) {
            const int k = p * 16 + (t >> 4);
            const int x = t & 15;
            uint4 o;
            o.x = pack2bf(T[x * 8 + 0][k], T[x * 8 + 1][k]);
            o.y = pack2bf(T[x * 8 + 2][k], T[x * 8 + 3][k]);
            o.z = pack2bf(T[x * 8 + 4][k], T[x * 8 + 5][k]);
            o.w = pack2bf(T[x * 8 + 6][k], T[x * 8 + 7][k]);
            const size_t rowbyte = ((size_t)bh * 1024 + s0 + k) * 256;
            const int boff = (x * 16) ^ ((k & 7) << 4);
            *(uint4*)((char*)Kt + rowbyte + boff) = o;
        }
    }
}

// ---------------------------------------------------------------------------
// MFMA flash attention v7. 256 blocks x 512 thr; q-tile 256; KVBLK 64
// triple-buffered, counted vmcnt(4). Swapped-QK, P in registers, bias as
// MFMA C-init. NEW: mask->bias folded in-block; Q loaded directly from
// global fp32 into fragments (no Qt prep).
// ---------------------------------------------------------------------------
__global__ __launch_bounds__(512, 2) void attn7(const float* __restrict__ queries,
                                                const ushort* __restrict__ Kt,
                                                const ushort* __restrict__ Vbf,
                                                const unsigned* __restrict__ mask,
                                                ushort* __restrict__ hidT) {
    __shared__ __align__(16) char SMEM[102416];
    // K: 3 x [64][128] (16 KB) at 0; V: 3 x [128][64] at 49152; bias at 98304
    float* biasS = (float*)(SMEM + 98304);
    int* flg = (int*)(SMEM + 102400);

    const int t = threadIdx.x, l = t & 63, w = t >> 6;   // w = 0..7
    const int kk = l & 15, g = l >> 4;

    const int bid = blockIdx.x;
    const int vid = (bid & 7) * 32 + (bid >> 3);   // XCD-affine (256 blocks)
    const int bh = vid >> 2, qt = vid & 3;
    const int b = bh >> 4, hh = bh & 15;
    const int q0 = qt * 256;
    const size_t bhbase = (size_t)bh * 1024;

    // ---- mask -> biasS, per-block dtype detection ----
    if (t == 0) { flg[0] = 0; flg[1] = 0; }
    __syncthreads();
    {
        int a = 0, c = 0;
        for (int i = t; i < 1024; i += 512) {
            unsigned vv = mask[i];
            if (vv != 0u && vv != 1u) a = 1;
            if (vv != 0u && vv != 0x3F800000u) c = 1;
        }
        if (a) atomicOr(&flg[0], 1);
        if (c) atomicOr(&flg[1], 1);
        __syncthreads();
        const int mode = flg[0] ? (flg[1] ? 1 : 2) : 0;
        const int* mi = (const int*)mask;
        const unsigned char* mb = (const unsigned char*)mask;
        const float* mf = (const float*)mask;
        for (int i = t; i < 1024; i += 512) {
            bool on;
            if (mode == 0)      on = (mi[b * 1024 + i] != 0);
            else if (mode == 1) on = (mb[b * 1024 + i] != 0);
            else                on = (mf[b * 1024 + i] != 0.0f);
            biasS[i] = on ? 0.0f : -1e30f;
        }
    }

    // ---- Q fragments direct from global fp32 [d][S] (once per block) ----
    const float* Qb = queries + ((size_t)(b * Cc + hh * Dd)) * Ss;
    bf16x8 qf[2][4];
#pragma unroll
    for (int qs = 0; qs < 2; ++qs)
#pragma unroll
        for (int dc = 0; dc < 4; ++dc) {
            const int q = q0 + w * 32 + qs * 16 + kk;
            float v0 = Qb[(size_t)(dc * 32 + g * 8 + 0) * Ss + q];
            float v1 = Qb[(size_t)(dc * 32 + g * 8 + 1) * Ss + q];
            float v2 = Qb[(size_t)(dc * 32 + g * 8 + 2) * Ss + q];
            float v3 = Qb[(size_t)(dc * 32 + g * 8 + 3) * Ss + q];
            float v4 = Qb[(size_t)(dc * 32 + g * 8 + 4) * Ss + q];
            float v5 = Qb[(size_t)(dc * 32 + g * 8 + 5) * Ss + q];
            float v6 = Qb[(size_t)(dc * 32 + g * 8 + 6) * Ss + q];
            float v7 = Qb[(size_t)(dc * 32 + g * 8 + 7) * Ss + q];
            uint4 u;
            u.x = pack2bf(v0 * QSCALE, v1 * QSCALE);
            u.y = pack2bf(v2 * QSCALE, v3 * QSCALE);
            u.z = pack2bf(v4 * QSCALE, v5 * QSCALE);
            u.w = pack2bf(v6 * QSCALE, v7 * QSCALE);
            qf[qs][dc] = *(bf16x8*)&u;
        }

    float lrun[2] = {0.0f, 0.0f};
    f32x4 hacc[2][8];
#pragma unroll
    for (int qs = 0; qs < 2; ++qs)
#pragma unroll
        for (int i = 0; i < 8; ++i) hacc[qs][i] = (f32x4){0.f, 0.f, 0.f, 0.f};

#define ATTN_STAGE(bufi, cki)                                                   \
    {                                                                           \
        const int k0n = (cki) * 64;                                             \
        ushort* Kd = (ushort*)SMEM + (bufi) * 8192;                             \
        ushort* Vd = (ushort*)(SMEM + 49152) + (bufi) * 8192;                   \
        _Pragma("unroll")                                                       \
        for (int ii = 0; ii < 4; ++ii) {                                        \
            const int inst = ii * 8 + w;                                        \
            if (inst < 16) {                                                    \
                gld16(Kt + (bhbase + k0n + inst * 4 + (l >> 4)) * 128 +         \
                          (l & 15) * 8,                                         \
                      Kd + inst * 512);                                         \
            } else {                                                            \
                const int i2 = inst - 16;                                       \
                gld16(Vbf + ((size_t)bh * 128 + i2 * 8 + (l >> 3)) * 1024 +     \
                          k0n + (l & 7) * 8,                                    \
                      Vd + i2 * 512);                                           \
            }                                                                   \
        }                                                                       \
    }

#define ATTN_COMPUTE(bi, ck)                                                     \
    {                                                                            \
        const int k0 = (ck) * 64;                                                \
        const ushort* KTb = (const ushort*)SMEM + (bi) * 8192;                   \
        const ushort* Vsb = (const ushort*)(SMEM + 49152) + (bi) * 8192;         \
        f32x4 sc[2][4];                                                          \
        __builtin_amdgcn_s_setprio(1);                                           \
        _Pragma("unroll")                                                        \
        for (int ns = 0; ns < 4; ++ns) {                                         \
            const f32x4 ci = *(const f32x4*)&biasS[k0 + ns * 16 + g * 4];        \
            bf16x8 kf[4];                                                        \
            const ushort* kr = KTb + (ns * 16 + kk) * 128;                       \
            _Pragma("unroll")                                                    \
            for (int dc = 0; dc < 4; ++dc)                                       \
                kf[dc] = *(const bf16x8*)(kr +                                   \
                             ((dc * 32 + g * 8) ^ ((kk & 7) << 3)));             \
            _Pragma("unroll")                                                    \
            for (int qs = 0; qs < 2; ++qs) {                                     \
                f32x4 a = ci;                                                    \
                _Pragma("unroll")                                                \
                for (int dc = 0; dc < 4; ++dc)                                   \
                    a = __builtin_amdgcn_mfma_f32_16x16x32_bf16(                 \
                        kf[dc], qf[qs][dc], a, 0, 0, 0);                         \
                sc[qs][ns] = a;                                                  \
            }                                                                    \
        }                                                                        \
        __builtin_amdgcn_s_setprio(0);                                           \
        bf16x8 pb[2][2];                                                         \
        _Pragma("unroll")                                                        \
        for (int qs = 0; qs < 2; ++qs) {                                         \
            float pv[4][4];                                                      \
            float s = 0.0f;                                                      \
            _Pragma("unroll")                                                    \
            for (int ns = 0; ns < 4; ++ns) {                                     \
                _Pragma("unroll")                                                \
                for (int r = 0; r < 4; ++r) {                                    \
                    float p = exp2f(sc[qs][ns][r]);                              \
                    pv[ns][r] = p;                                               \
                    s += p;                                                      \
                }                                                                \
            }                                                                    \
            lrun[qs] += s;                                                       \
            _Pragma("unroll")                                                    \
            for (int kh = 0; kh < 2; ++kh) {                                     \
                bf16x8 vpk;                                                      \
                _Pragma("unroll")                                                \
                for (int j = 0; j < 8; ++j)                                      \
                    vpk[j] = (__bf16)pv[2 * kh + (j >> 2)][j & 3];               \
                pb[qs][kh] = vpk;                                                \
            }                                                                    \
        }                                                                        \
        __builtin_amdgcn_s_setprio(1);                                           \
        _Pragma("unroll")                                                        \
        for (int kh = 0; kh < 2; ++kh) {                                         \
            _Pragma("unroll")                                                    \
            for (int ds = 0; ds < 8; ++ds) {                                     \
                bf16x8 vf = *(const bf16x8*)(Vsb + (ds * 16 + kk) * 64 +         \
                                 ((kh * 32 + g * 8) ^ ((kk & 7) << 3)));         \
                hacc[0][ds] = __builtin_amdgcn_mfma_f32_16x16x32_bf16(           \
                    vf, pb[0][kh], hacc[0][ds], 0, 0, 0);                        \
                hacc[1][ds] = __builtin_amdgcn_mfma_f32_16x16x32_bf16(           \
                    vf, pb[1][kh], hacc[1][ds], 0, 0, 0);                        \
            }                                                                    \
        }                                                                        \
        __builtin_amdgcn_s_setprio(0);                                           \
    }

    // prologue: 2 tiles in flight; wait for tile 0 only (counted)
    ATTN_STAGE(0, 0);
    ATTN_STAGE(1, 1);
    asm volatile("s_waitcnt vmcnt(4)" ::: "memory");
    __builtin_amdgcn_s_barrier();

    int cb = 0, sb = 2;
    for (int ck = 0; ck < 14; ++ck) {
        ATTN_STAGE(sb, ck + 2);
        ATTN_COMPUTE(cb, ck);
        asm volatile("s_waitcnt vmcnt(4)" ::: "memory");
        __builtin_amdgcn_s_barrier();
        cb = (cb == 2) ? 0 : cb + 1;
        sb = (sb == 2) ? 0 : sb + 1;
    }
    ATTN_COMPUTE(cb, 14);
    asm volatile("s_waitcnt vmcnt(0)" ::: "memory");
    __builtin_amdgcn_s_barrier();
    cb = (cb == 2) ? 0 : cb + 1;
    ATTN_COMPUTE(cb, 15);
#undef ATTN_STAGE
#undef ATTN_COMPUTE

    float linv[2];
#pragma unroll
    for (int qs = 0; qs < 2; ++qs) {
        float s = lrun[qs];
        s += __shfl_xor(s, 16);
        s += __shfl_xor(s, 32);
        linv[qs] = 1.0f / s;
    }

    __syncthreads();   // done with K/V buffers; reuse as [256 q][128 d] stage
    {
        ushort* hs = (ushort*)SMEM;
#pragma unroll
        for (int qs = 0; qs < 2; ++qs) {
            const int row = w * 32 + qs * 16 + kk;
#pragma unroll
            for (int ds = 0; ds < 8; ++ds) {
                uint2 pk;
                pk.x = pack2bf(hacc[qs][ds][0] * linv[qs], hacc[qs][ds][1] * linv[qs]);
                pk.y = pack2bf(hacc[qs][ds][2] * linv[qs], hacc[qs][ds][3] * linv[qs]);
                const int off = row * 256 + ((ds * 32 + g * 8) ^ ((row & 7) << 4));
                *(uint2*)((char*)hs + off) = pk;
            }
        }
    }
    __syncthreads();

    const char* hsb = (const char*)SMEM;
#pragma unroll
    for (int it = 0; it < 8; ++it) {
        const int idx = it * 512 + t;                  // 0..4095
        const int q = idx >> 4, x = idx & 15;
        uint4 vv = *(const uint4*)(hsb + q * 256 + x * 16);
        *(uint4*)((char*)hidT + ((size_t)(b * Ss + q0 + q)) * 4096 + hh * 256 + x * 16) = vv;
    }
}

// ---------------------------------------------------------------------------
// proj5: out[2048][4096] = W @ hidT^T. BM=128, BN=256, BK=64, 512 thr
// (8 waves 2Mx4N, per-wave 64x64). Template-faithful schedule: 2 phases per
// K-tile, 16 MFMA/phase, ds_read ∥ stage-issue ∥ MFMA in every phase,
// 3-buffer LDS (144 KB), vmcnt(6) once per K-tile. 256 blocks (1/CU).
// ---------------------------------------------------------------------------
__global__ __launch_bounds__(512, 2) void proj5(const ushort* __restrict__ Wbf,
                                                const ushort* __restrict__ hidT,
                                                float* __restrict__ out) {
    __shared__ __align__(16) char SMEM[147456];
    // A: 3 x [128][64] = 16 KB at 0..49152; B: 3 x [256][64] = 32 KB at 49152+
    const int t = threadIdx.x, l = t & 63, w = t >> 6;
    const int kk = l & 15, g = l >> 4;
    const int wr = w >> 2, wc = w & 3;

    const int bid = blockIdx.x;
    const int vid = (bid & 7) * 32 + (bid >> 3);   // 256 blocks, XCD-bijective
    const int o0 = (vid & 15) * 128;               // 16 M-tiles
    const int n0 = (vid >> 4) * 256;               // 16 N-tiles

    f32x4 acc[4][4];
#pragma unroll
    for (int i = 0; i < 4; ++i)
#pragma unroll
        for (int j = 0; j < 4; ++j) acc[i][j] = (f32x4){0.f, 0.f, 0.f, 0.f};

    const int swz = (kk & 7) << 3;

#define P5_STAGE_A(st, ks)                                                      \
    {                                                                           \
        ushort* Ad = (ushort*)SMEM + (st) * 8192;                               \
        _Pragma("unroll")                                                       \
        for (int ii = 0; ii < 2; ++ii) {                                        \
            const int idx = ii * 512 + t;                                       \
            gld16(Wbf + (size_t)(o0 + (idx >> 3)) * 2048 + (ks) * 64 +          \
                      (idx & 7) * 8,                                            \
                  Ad + idx * 8);                                                \
        }                                                                       \
    }
#define P5_STAGE_B(st, ks, p)                                                   \
    {                                                                           \
        ushort* Bd = (ushort*)(SMEM + 49152) + (st) * 16384;                    \
        _Pragma("unroll")                                                       \
        for (int jj = (p) * 2; jj < (p) * 2 + 2; ++jj) {                        \
            const int idx = jj * 512 + t;                                       \
            gld16(hidT + (size_t)(n0 + (idx >> 3)) * 2048 + (ks) * 64 +         \
                      (idx & 7) * 8,                                            \
                  Bd + idx * 8);                                                \
        }                                                                       \
    }
#define P5_READ(dcv)                                                            \
    _Pragma("unroll")                                                           \
    for (int ms = 0; ms < 4; ++ms)                                              \
        af[ms] = *(const bf16x8*)&Ab[(wr * 64 + ms * 16 + kk) * 64 +            \
                                     (((dcv) * 32 + g * 8) ^ swz)];             \
    _Pragma("unroll")                                                           \
    for (int ns = 0; ns < 4; ++ns)                                              \
        bfr[ns] = *(const bf16x8*)&Bb[(wc * 64 + ns * 16 + kk) * 64 +           \
                                      (((dcv) * 32 + g * 8) ^ swz)];
#define P5_MFMA()                                                               \
    __builtin_amdgcn_s_setprio(1);                                              \
    _Pragma("unroll")                                                           \
    for (int ms = 0; ms < 4; ++ms)                                              \
        _Pragma("unroll")                                                       \
        for (int ns = 0; ns < 4; ++ns)                                          \
            acc[ms][ns] = __builtin_amdgcn_mfma_f32_16x16x32_bf16(              \
                af[ms], bfr[ns], acc[ms][ns], 0, 0, 0);                         \
    __builtin_amdgcn_s_setprio(0);

    // prologue: stage iterations 0 and 1; wait for iter 0 only
    P5_STAGE_A(0, 0); P5_STAGE_B(0, 0, 0); P5_STAGE_B(0, 0, 1);
    P5_STAGE_A(1, 1); P5_STAGE_B(1, 1, 0); P5_STAGE_B(1, 1, 1);
    asm volatile("s_waitcnt vmcnt(6)" ::: "memory");
    __builtin_amdgcn_s_barrier();

    int ct = 0, st2 = 2;
    for (int tt = 0; tt < 32; ++tt) {
        const ushort* Ab = (const ushort*)SMEM + ct * 8192;
        const ushort* Bb = (const ushort*)(SMEM + 49152) + ct * 16384;
        bf16x8 af[4], bfr[4];

        // ---- phase 0 (dc=0): ds_read 8 ∥ stage A + B-half ----
        P5_READ(0);
        if (tt < 30) { P5_STAGE_A(st2, tt + 2); P5_STAGE_B(st2, tt + 2, 0); }
        __builtin_amdgcn_s_barrier();
        asm volatile("s_waitcnt lgkmcnt(0)" ::: "memory");
        P5_MFMA();
        __builtin_amdgcn_s_barrier();

        // ---- phase 1 (dc=1): ds_read 8 ∥ stage B-half; counted vmcnt ----
        P5_READ(1);
        if (tt < 30) P5_STAGE_B(st2, tt + 2, 1);
        if (tt < 30) { asm volatile("s_waitcnt vmcnt(6)" ::: "memory"); }
        else         { asm volatile("s_waitcnt vmcnt(0)" ::: "memory"); }
        __builtin_amdgcn_s_barrier();
        asm volatile("s_waitcnt lgkmcnt(0)" ::: "memory");
        P5_MFMA();
        __builtin_amdgcn_s_barrier();

        ct = (ct == 2) ? 0 : ct + 1;
        st2 = (st2 == 2) ? 0 : st2 + 1;
    }
#undef P5_STAGE_A
#undef P5_STAGE_B
#undef P5_READ
#undef P5_MFMA

#pragma unroll
    for (int ms = 0; ms < 4; ++ms)
#pragma unroll
        for (int ns = 0; ns < 4; ++ns) {
            const int o = o0 + wr * 64 + ms * 16 + g * 4;
            const int n = n0 + wc * 64 + ns * 16 + kk;
            const int bb = n >> 10, qq = n & 1023;
            float* op = out + ((size_t)(bb * Cc + o)) * Ss + qq;
#pragma unroll
            for (int r = 0; r < 4; ++r) op[(size_t)r * Ss] = acc[ms][ns][r];
        }
}

extern "C" void kernel_launch(void* const* d_in, const int* in_sizes, int n_in,
                              void* d_out, int out_size, void* d_ws, size_t ws_size,
                              hipStream_t stream) {
    const float*    keys    = (const float*)d_in[0];
    const float*    values  = (const float*)d_in[1];
    const float*    queries = (const float*)d_in[2];
    const unsigned* mask    = (const unsigned*)d_in[3];
    const float*    w_out   = (const float*)d_in[4];
    float* out = (float*)d_out;

    char* ws = (char*)d_ws;
    ushort* Wbf  = (ushort*)ws;                             // 8 MB
    ushort* Kt   = (ushort*)(ws + (8u << 20));              // 16 MB
    ushort* Vbf  = (ushort*)(ws + (24u << 20));             // 16 MB
    ushort* hidT = (ushort*)(ws + (40u << 20));             // 16 MB

    hipLaunchKernelGGL(prep_all, dim3(7168), dim3(256), 0, stream,
                       w_out, values, keys, Wbf, Vbf, Kt);
    hipLaunchKernelGGL(attn7, dim3(256), dim3(512), 0, stream,
                       queries, Kt, Vbf, mask, hidT);
    hipLaunchKernelGGL(proj5, dim3(256), dim3(512), 0, stream,
                       Wbf, hidT, out);
}